// Round 4
// baseline (51.896 us; speedup 1.0000x reference)
//
#include <hip/hip_runtime.h>
#include <hip/hip_bf16.h>

// ST-GCN spatial graph conv, fused two-stage MFMA (bf16 in, f32 accum), TB=2.
//   Stage1: F^T[tv][kc] = X^T[tv][ci] @ W^T[ci][kc]   (per block: n, 2 t's)
//           A-frags loaded DIRECT from global x (no Xs LDS).
//   Stage2: out_t^T[w][c] = Ahat[w][khat] @ F_t[khat][c], khat = k*32+v (padded;
//           Ahat zeros kill v>=25 pad garbage in F).
//
// LDS (32000 B -> 4 blocks/CU = 32 waves, the HW cap):
//   [0,24576)      Ws[192 o][64 ci] bf16 chunk^=(o&7)  — aliased by
//                  Fs[192 kc][64 tv] bf16 chunk^=(kc&7) (Ws dead after stage-1)
//   [24576,31232)  As[32 w][104 pad] bf16
//   [31232,32000)  bias f32[192]

#define CIN   64
#define T_    300
#define V_    25
#define OC    192     // K*C_OUT
#define COUT  64
#define TB    2
#define NBLK  (32 * (T_ / TB))   // 4800

typedef short  bf16x8 __attribute__((ext_vector_type(8)));
typedef float  f32x4  __attribute__((ext_vector_type(4)));
typedef unsigned int u32x2 __attribute__((ext_vector_type(2)));

__device__ __forceinline__ unsigned short cvt_bf16(float f) {   // HW RNE cvt
    union { __hip_bfloat16 h; unsigned short u; } cv;
    cv.h = __float2bfloat16(f);
    return cv.u;
}

#define WS_OFF    0
#define FS_OFF    0
#define AS_OFF    24576
#define BIAS_OFF  31232
#define SMEM_BYTES 32000

__global__ __launch_bounds__(512, 8) void gcn_mfma(
    const float* __restrict__ x, const float* __restrict__ W,
    const float* __restrict__ bias, const float* __restrict__ A,
    float* __restrict__ out)
{
    __shared__ __align__(16) unsigned char smem[SMEM_BYTES];

    const int tid = threadIdx.x;
    const int bx  = blockIdx.x;
    const int n   = bx / (T_ / TB);
    const int t0  = (bx % (T_ / TB)) * TB;

    const int wv = tid >> 6, l = tid & 63, lr = l & 15, lq = l >> 4;
    const int m  = wv >> 1;              // M-tile (tv rows 16m..16m+15)

    // ---- issue direct x loads for stage-1 A-frags
    //      tv row = m*16+lr : tt = m>>1, v = (m&1)*16 + lr
    const int tt = m >> 1;
    const int v  = (m & 1) * 16 + lr;
    const int vc = v > 24 ? 24 : v;      // clamp; pad rows killed by Ahat zeros
    const float* xb = x + ((size_t)(n * CIN + lq * 8) * T_ + (t0 + tt)) * V_ + vc;
    float xr[16];
    #pragma unroll
    for (int ks = 0; ks < 2; ++ks)
        #pragma unroll
        for (int e = 0; e < 8; ++e)
            xr[ks * 8 + e] = xb[(size_t)(ks * 32 + e) * (T_ * V_)];

    // ---- stage Ws: W[o][ci] f32 -> bf16, natural layout, 16B chunks ^= (o&7)
    for (int ch = tid; ch < OC * 8; ch += 512) {              // 1536 chunks
        const int o = ch >> 3, j = ch & 7;
        const float4 wa = *reinterpret_cast<const float4*>(W + (size_t)o * CIN + j * 8);
        const float4 wb = *reinterpret_cast<const float4*>(W + (size_t)o * CIN + j * 8 + 4);
        const float* wea = reinterpret_cast<const float*>(&wa);
        const float* web = reinterpret_cast<const float*>(&wb);
        bf16x8 s;
        #pragma unroll
        for (int e = 0; e < 4; ++e) {
            s[e]     = (short)cvt_bf16(wea[e]);
            s[4 + e] = (short)cvt_bf16(web[e]);
        }
        *reinterpret_cast<bf16x8*>(smem + WS_OFF + o * 128 + ((j ^ (o & 7)) << 4)) = s;
    }
    // ---- stage Ahat[w][k*32+v] = A[k][v][w], zero-padded, rows padded to 104 shorts
    for (int idx = tid; idx < 32 * 48; idx += 512) {          // u32 pairs
        const int wq = idx / 48, kh = (idx % 48) * 2;
        const int k = kh >> 5, vv = kh & 31;
        const float v0 = (wq < V_ && vv     < V_) ? A[k * (V_ * V_) + vv * V_ + wq]       : 0.f;
        const float v1 = (wq < V_ && vv + 1 < V_) ? A[k * (V_ * V_) + (vv + 1) * V_ + wq] : 0.f;
        const unsigned pk = (unsigned)cvt_bf16(v0) | ((unsigned)cvt_bf16(v1) << 16);
        *reinterpret_cast<unsigned*>(smem + AS_OFF + (wq * 104 + kh) * 2) = pk;
    }
    if (tid < OC) *reinterpret_cast<float*>(smem + BIAS_OFF + tid * 4) = bias[tid];
    __syncthreads();

    // ---- stage 1: wave wv -> M-tile m, N-tiles (wv&1)*6 .. +6
    f32x4 acc[6];
    #pragma unroll
    for (int i = 0; i < 6; ++i) acc[i] = (f32x4){0.f, 0.f, 0.f, 0.f};

    const int n0 = (wv & 1) * 6;
    #pragma unroll
    for (int ks = 0; ks < 2; ++ks) {
        bf16x8 afr;
        #pragma unroll
        for (int e = 0; e < 8; ++e) afr[e] = (short)cvt_bf16(xr[ks * 8 + e]);
        #pragma unroll
        for (int j = 0; j < 6; ++j) {
            const int o = (n0 + j) * 16 + lr;
            const bf16x8 bfr = *reinterpret_cast<bf16x8*>(
                smem + WS_OFF + o * 128 + (((ks * 4 + lq) ^ (o & 7)) << 4));
            acc[j] = __builtin_amdgcn_mfma_f32_16x16x32_bf16(afr, bfr, acc[j], 0, 0, 0);
        }
    }

    __syncthreads();   // stage-1 Ws reads done before Fs overwrites

    // ---- write F = acc + bias to Fs[kc][tv] bf16, swizzled
    const int tvb = m * 16 + lq * 4;
    #pragma unroll
    for (int j = 0; j < 6; ++j) {
        const int kc = (n0 + j) * 16 + lr;
        const float bb = *reinterpret_cast<const float*>(smem + BIAS_OFF + kc * 4);
        const unsigned short h0 = cvt_bf16(acc[j][0] + bb), h1 = cvt_bf16(acc[j][1] + bb);
        const unsigned short h2 = cvt_bf16(acc[j][2] + bb), h3 = cvt_bf16(acc[j][3] + bb);
        u32x2 pk;
        pk[0] = (unsigned)h0 | ((unsigned)h1 << 16);
        pk[1] = (unsigned)h2 | ((unsigned)h3 << 16);
        const int byte = FS_OFF + kc * 128 + ((((tvb >> 3) ^ (kc & 7)) << 4)) + (tvb & 7) * 2;
        *reinterpret_cast<u32x2*>(smem + byte) = pk;
    }
    __syncthreads();

    // ---- stage 2: wave -> out tile (mt: w-rows, nc: c-cols), loop t
    const int mt = wv >> 2, nc = wv & 3;
    bf16x8 afr2[3];
    #pragma unroll
    for (int ks = 0; ks < 3; ++ks)
        afr2[ks] = *reinterpret_cast<bf16x8*>(
            smem + AS_OFF + ((mt * 16 + lr) * 104 + ks * 32 + lq * 8) * 2);

    const int c  = nc * 16 + lr;
    const int w0 = mt * 16 + lq * 4;
    #pragma unroll
    for (int t = 0; t < TB; ++t) {
        f32x4 a2 = (f32x4){0.f, 0.f, 0.f, 0.f};
        #pragma unroll
        for (int ks = 0; ks < 3; ++ks) {
            const int kc = ks * 64 + c;
            const bf16x8 bfr = *reinterpret_cast<bf16x8*>(
                smem + FS_OFF + kc * 128 + ((((t * 4 + lq) ^ (kc & 7)) << 4)));
            a2 = __builtin_amdgcn_mfma_f32_16x16x32_bf16(afr2[ks], bfr, a2, 0, 0, 0);
        }
        float* op = out + ((size_t)(n * COUT + c) * T_ + (t0 + t)) * V_;
        if (w0 + 3 < V_) {
            #pragma unroll
            for (int e = 0; e < 4; ++e) op[w0 + e] = a2[e];
        } else {
            #pragma unroll
            for (int e = 0; e < 4; ++e) if (w0 + e < V_) op[w0 + e] = a2[e];
        }
    }
}

extern "C" void kernel_launch(void* const* d_in, const int* in_sizes, int n_in,
                              void* d_out, int out_size, void* d_ws, size_t ws_size,
                              hipStream_t stream) {
    const float* x    = (const float*)d_in[0];
    const float* W    = (const float*)d_in[1];
    const float* bias = (const float*)d_in[2];
    const float* A    = (const float*)d_in[3];
    float* out = (float*)d_out;

    hipLaunchKernelGGL(gcn_mfma, dim3(NBLK), dim3(512), 0, stream, x, W, bias, A, out);
}